// Round 8
// baseline (230.463 us; speedup 1.0000x reference)
//
#include <hip/hip_runtime.h>

#define NOUT 7
#define NROI 512
#define NCH 256
#define BINS (NOUT * NOUT)        // 49
#define ROI_ELEMS (NCH * BINS)    // 12544
#define EPB 512                   // elements per block (2 per thread)
#define CHUNKS ((ROI_ELEMS + EPB - 1) / EPB)   // 25

// float4 with 4-byte alignment: dword-aligned but not 16B-aligned loads
// (gfx950 handles this; R3 validated dwordx2 at 4B alignment).
typedef float f4u __attribute__((ext_vector_type(4), aligned(4)));

__global__ __launch_bounds__(256, 6) void roi_pool_kernel(
    const float* __restrict__ x2,
    const float* __restrict__ x3,
    const float* __restrict__ x4,
    const float* __restrict__ x5,
    const float* __restrict__ boxes,
    float* __restrict__ out)
{
    const int r     = blockIdx.x;  // roi 0..511
    const int chunk = blockIdx.y;  // 0..24
    const int t     = threadIdx.x; // 0..255

    // y (per ph): sdyA = { asfloat(y0a*W), asfloat(y0b*W), rw0, rw1 },
    //             sdyB = { rw2, rw3 }   rw = 0.25*valid_y*{1-fy, fy} per sample
    // x fast (per pw): sdxW = xw[4] (both samples' lerp+valid weights in a
    //                  4-wide span), sdxC = span base xb
    // x slow (per pw): sdxP = { asfloat(ia), asfloat(ib), wa0, wa1 },
    //                  sdxQ = { wb0, wb1 }
    __shared__ float4 sdyA[NOUT];
    __shared__ float2 sdyB[NOUT];
    __shared__ float4 sdxW[NOUT];
    __shared__ int    sdxC[NOUT];
    __shared__ float4 sdxP[NOUT];
    __shared__ float2 sdxQ[NOUT];
    __shared__ int    sfast;
    __shared__ const float* sbase;   // feat + b*C*H*W
    __shared__ int sW, sHW;

    if (t < 32) {
        const float bx1 = boxes[4 * r + 0];
        const float by1 = boxes[4 * r + 1];
        const float bx2 = boxes[4 * r + 2];
        const float by2 = boxes[4 * r + 3];
        const float sz  = sqrtf((bx2 - bx1) * (by2 - by1));
        float lvlf = floorf(4.0f + log2f(sz / 224.0f + 1e-8f));
        lvlf = fminf(fmaxf(lvlf, 2.0f), 5.0f);
        const int level = (int)lvlf - 2;

        int H, W; float scale; const float* feat;
        if (level == 0)      { H = 200; W = 304; scale = 0.25f;    feat = x2; }
        else if (level == 1) { H = 100; W = 152; scale = 0.125f;   feat = x3; }
        else if (level == 2) { H = 50;  W = 76;  scale = 0.0625f;  feat = x4; }
        else                 { H = 25;  W = 38;  scale = 0.03125f; feat = x5; }

        const float X1 = bx1 * scale - 0.5f;
        const float Y1 = by1 * scale - 0.5f;
        const float X2 = bx2 * scale - 0.5f;
        const float Y2 = by2 * scale - 0.5f;
        const float bw = (X2 - X1) * (1.0f / NOUT);
        const float bh = (Y2 - Y1) * (1.0f / NOUT);

        bool okl = true;   // per-lane fast-path fitness (x lanes only)

        if (t < NOUT) {
            const int ph = t;
            float ca = Y1 + ((float)ph + 0.25f) * bh;
            float cb = Y1 + ((float)ph + 0.75f) * bh;
            const float va = ((ca >= -1.0f) && (ca <= (float)H)) ? 0.25f : 0.0f;
            const float vb = ((cb >= -1.0f) && (cb <= (float)H)) ? 0.25f : 0.0f;
            ca = fminf(fmaxf(ca, 0.0f), (float)(H - 1));
            cb = fminf(fmaxf(cb, 0.0f), (float)(H - 1));
            const int ia = min((int)floorf(ca), H - 2);   // i1 = i0+1 normalization
            const int ib = min((int)floorf(cb), H - 2);
            const float fya = ca - (float)ia;
            const float fyb = cb - (float)ib;
            sdyA[ph] = make_float4(__int_as_float(ia * W), __int_as_float(ib * W),
                                   va * (1.0f - fya), va * fya);
            sdyB[ph] = make_float2(vb * (1.0f - fyb), vb * fyb);
        } else if (t >= 8 && t < 8 + NOUT) {
            const int pw = t - 8;
            float ca = X1 + ((float)pw + 0.25f) * bw;
            float cb = X1 + ((float)pw + 0.75f) * bw;
            const float va = ((ca >= -1.0f) && (ca <= (float)W)) ? 1.0f : 0.0f;
            const float vb = ((cb >= -1.0f) && (cb <= (float)W)) ? 1.0f : 0.0f;
            ca = fminf(fmaxf(ca, 0.0f), (float)(W - 1));
            cb = fminf(fmaxf(cb, 0.0f), (float)(W - 1));
            const int ia = min((int)floorf(ca), W - 2);
            const int ib = min((int)floorf(cb), W - 2);
            const float fxa = ca - (float)ia;
            const float fxb = cb - (float)ib;

            sdxP[pw] = make_float4(__int_as_float(ia), __int_as_float(ib),
                                   va * (1.0f - fxa), va * fxa);
            sdxQ[pw] = make_float2(vb * (1.0f - fxb), vb * fxb);

            const int xb = min(ia, W - 4);
            const int d0 = ia - xb;          // 0..2
            const int d1 = ib - xb;          // >= d0; fast iff <= 2
            okl = (d1 <= 2);
            float xw[4];
            #pragma unroll
            for (int k = 0; k < 4; ++k) {
                float w = 0.0f;
                w += va * ((k == d0) ? (1.0f - fxa) : (k == d0 + 1) ? fxa : 0.0f);
                w += vb * ((k == d1) ? (1.0f - fxb) : (k == d1 + 1) ? fxb : 0.0f);
                xw[k] = w;
            }
            sdxW[pw] = make_float4(xw[0], xw[1], xw[2], xw[3]);
            sdxC[pw] = xb;
        }

        const unsigned long long bal = __ballot(okl);
        if (t == 31) {
            const int b = r >> 8;
            sbase = feat + (size_t)b * NCH * H * W;
            sW    = W;
            sHW   = H * W;
            sfast = (((bal >> 8) & 0x7Full) == 0x7Full);
        }
    }
    __syncthreads();

    const float* const base = sbase;
    const int W  = sW;
    const int HW = sHW;
    const int fast = sfast;

    // two output elements per thread: iA and iA+256 (tail chunk drops elem B)
    const int iA = chunk * EPB + t;
    const bool wB = (iA + 256) < ROI_ELEMS;
    const int iB = wB ? (iA + 256) : iA;

    const int cA   = iA / BINS;
    const int binA = iA - cA * BINS;
    const int phA  = binA / NOUT;
    const int pwA  = binA - phA * NOUT;
    const int cB   = iB / BINS;
    const int binB = iB - cB * BINS;
    const int phB  = binB / NOUT;
    const int pwB  = binB - phB * NOUT;

    const float4 yAA = sdyA[phA];
    const float2 yBA = sdyB[phA];
    const float4 yAB = sdyA[phB];
    const float2 yBB = sdyB[phB];

    const float* const fA  = base + (size_t)cA * HW;
    const float* const paA = fA + __float_as_int(yAA.x);
    const float* const pbA = fA + __float_as_int(yAA.y);
    const float* const fB  = base + (size_t)cB * HW;
    const float* const paB = fB + __float_as_int(yAB.x);
    const float* const pbB = fB + __float_as_int(yAB.y);

    float accA, accB;
    if (fast) {
        const float4 xwA = sdxW[pwA];
        const int    xbA = sdxC[pwA];
        const float4 xwB = sdxW[pwB];
        const int    xbB = sdxC[pwB];
        // all 8 loads independent -> issued back-to-back, 8 in flight
        const f4u a0 = *(const f4u*)(paA + xbA);
        const f4u a1 = *(const f4u*)(paA + W + xbA);
        const f4u a2 = *(const f4u*)(pbA + xbA);
        const f4u a3 = *(const f4u*)(pbA + W + xbA);
        const f4u b0 = *(const f4u*)(paB + xbB);
        const f4u b1 = *(const f4u*)(paB + W + xbB);
        const f4u b2 = *(const f4u*)(pbB + xbB);
        const f4u b3 = *(const f4u*)(pbB + W + xbB);
        const float dA0 = a0.x * xwA.x + a0.y * xwA.y + a0.z * xwA.z + a0.w * xwA.w;
        const float dA1 = a1.x * xwA.x + a1.y * xwA.y + a1.z * xwA.z + a1.w * xwA.w;
        const float dA2 = a2.x * xwA.x + a2.y * xwA.y + a2.z * xwA.z + a2.w * xwA.w;
        const float dA3 = a3.x * xwA.x + a3.y * xwA.y + a3.z * xwA.z + a3.w * xwA.w;
        const float dB0 = b0.x * xwB.x + b0.y * xwB.y + b0.z * xwB.z + b0.w * xwB.w;
        const float dB1 = b1.x * xwB.x + b1.y * xwB.y + b1.z * xwB.z + b1.w * xwB.w;
        const float dB2 = b2.x * xwB.x + b2.y * xwB.y + b2.z * xwB.z + b2.w * xwB.w;
        const float dB3 = b3.x * xwB.x + b3.y * xwB.y + b3.z * xwB.z + b3.w * xwB.w;
        accA = yAA.z * dA0 + yAA.w * dA1 + yBA.x * dA2 + yBA.y * dA3;
        accB = yAB.z * dB0 + yAB.w * dB1 + yBB.x * dB2 + yBB.y * dB3;
    } else {
        const float4 xpA = sdxP[pwA];
        const float2 xqA = sdxQ[pwA];
        const float4 xpB = sdxP[pwB];
        const float2 xqB = sdxQ[pwB];
        const int iaA = __float_as_int(xpA.x);
        const int ibA = __float_as_int(xpA.y);
        const int iaB = __float_as_int(xpB.x);
        const int ibB = __float_as_int(xpB.y);
        const float2 a0 = *(const float2*)(paA + iaA);
        const float2 a1 = *(const float2*)(paA + ibA);
        const float2 a2 = *(const float2*)(paA + W + iaA);
        const float2 a3 = *(const float2*)(paA + W + ibA);
        const float2 a4 = *(const float2*)(pbA + iaA);
        const float2 a5 = *(const float2*)(pbA + ibA);
        const float2 a6 = *(const float2*)(pbA + W + iaA);
        const float2 a7 = *(const float2*)(pbA + W + ibA);
        const float2 b0 = *(const float2*)(paB + iaB);
        const float2 b1 = *(const float2*)(paB + ibB);
        const float2 b2 = *(const float2*)(paB + W + iaB);
        const float2 b3 = *(const float2*)(paB + W + ibB);
        const float2 b4 = *(const float2*)(pbB + iaB);
        const float2 b5 = *(const float2*)(pbB + ibB);
        const float2 b6 = *(const float2*)(pbB + W + iaB);
        const float2 b7 = *(const float2*)(pbB + W + ibB);
        const float dA0 = a0.x * xpA.z + a0.y * xpA.w + a1.x * xqA.x + a1.y * xqA.y;
        const float dA1 = a2.x * xpA.z + a2.y * xpA.w + a3.x * xqA.x + a3.y * xqA.y;
        const float dA2 = a4.x * xpA.z + a4.y * xpA.w + a5.x * xqA.x + a5.y * xqA.y;
        const float dA3 = a6.x * xpA.z + a6.y * xpA.w + a7.x * xqA.x + a7.y * xqA.y;
        const float dB0 = b0.x * xpB.z + b0.y * xpB.w + b1.x * xqB.x + b1.y * xqB.y;
        const float dB1 = b2.x * xpB.z + b2.y * xpB.w + b3.x * xqB.x + b3.y * xqB.y;
        const float dB2 = b4.x * xpB.z + b4.y * xpB.w + b5.x * xqB.x + b5.y * xqB.y;
        const float dB3 = b6.x * xpB.z + b6.y * xpB.w + b7.x * xqB.x + b7.y * xqB.y;
        accA = yAA.z * dA0 + yAA.w * dA1 + yBA.x * dA2 + yBA.y * dA3;
        accB = yAB.z * dB0 + yAB.w * dB1 + yBB.x * dB2 + yBB.y * dB3;
    }

    float* const outr = out + (size_t)r * ROI_ELEMS;
    outr[iA] = accA;
    if (wB) outr[iB] = accB;
}

extern "C" void kernel_launch(void* const* d_in, const int* in_sizes, int n_in,
                              void* d_out, int out_size, void* d_ws, size_t ws_size,
                              hipStream_t stream) {
    const float* x2    = (const float*)d_in[0];
    const float* x3    = (const float*)d_in[1];
    const float* x4    = (const float*)d_in[2];
    const float* x5    = (const float*)d_in[3];
    const float* boxes = (const float*)d_in[4];
    float* out = (float*)d_out;

    dim3 grid(NROI, CHUNKS);
    roi_pool_kernel<<<grid, 256, 0, stream>>>(x2, x3, x4, x5, boxes, out);
}